// Round 8
// baseline (46.274 us; speedup 1.0000x reference)
//
#include <hip/hip_runtime.h>
#include <stdint.h>

typedef short bf16x8 __attribute__((ext_vector_type(8)));
typedef float f32x16 __attribute__((ext_vector_type(16)));

#define EMB 256
#define HID 1024

// ---------------- SHA-256/224 primitives (proven R4-R7) ----------------
#define ROTR(x,n) (((x)>>(n))|((x)<<(32-(n))))
#define S0F(x) (ROTR((x),7)^ROTR((x),18)^((x)>>3))
#define S1F(x) (ROTR((x),17)^ROTR((x),19)^((x)>>10))

#define RND1(Kc, Wt) do {                                                          \
    uint32_t t1_ = sh + (ROTR(se,6)^ROTR(se,11)^ROTR(se,25))                       \
                   + ((se&sf)^(~se&sg)) + (Kc) + (Wt);                             \
    uint32_t t2_ = (ROTR(sa,2)^ROTR(sa,13)^ROTR(sa,22))                            \
                   + ((sa&sb)^(sa&sc)^(sb&sc));                                    \
    sh=sg; sg=sf; sf=se; se=sd+t1_; sd=sc; sc=sb; sb=sa; sa=t1_+t2_; } while (0)

#define WSXS(a,b,c,d) ((a) += S0F(b) + (c) + S1F(d))

__device__ __forceinline__ uint32_t rbf(float x) {
    uint32_t b = __float_as_uint(x);
    return (b + 0x7FFFu + ((b >> 16) & 1u)) >> 16;   // fp32 -> bf16 RNE
}
__device__ __forceinline__ uint4 pack8(float4 a, float4 b) {
    uint4 q;
    q.x = rbf(a.x) | (rbf(a.y) << 16);
    q.y = rbf(a.z) | (rbf(a.w) << 16);
    q.z = rbf(b.x) | (rbf(b.y) << 16);
    q.w = rbf(b.z) | (rbf(b.w) << 16);
    return q;
}

#define MFMA(av,bv,acc) __builtin_amdgcn_mfma_f32_32x32x16_bf16(av,bv,acc,0,0,0)

// Fully fused, 2 blocks/CU for wave-level overlap (the R6/R7 miss: 1 wave/SIMD
// exposed every latency; __syncthreads drains are covered by the co-resident
// block, per m114/m97 — no exotic barriers needed).
// Grid 512 x 256 threads. Block (bm = bid>>1): tokens [bm*64,+64),
// nh = bid&1: n in [nh*512,+512). LDS 64KB: A resident 32KB + B dbuf 2x16KB.
// B chunk c (c>>2 = n-sub of 128, c&3 = k-quarter of 64): [4 g][4 kf][64 l].
// Waves: m-group = wv>>1, n-group pair = (wv&1)*2 -> wave tile 32M x 64N,
// acc = 2 x f32x16 (32 VGPR).
__global__ __launch_bounds__(256, 2) void fused_kernel(const uint32_t* __restrict__ ids32,
                                                       const float* __restrict__ W,
                                                       const float* __restrict__ bias,
                                                       float* __restrict__ out) {
    __shared__ uint4 Albuf[2048];   // A: [2 g][16 kf][64 l] x 16B = 32KB
    __shared__ uint4 Blbuf[2048];   // B: 2 x [4 g][4 kf][64 l] x 16B = 32KB
    uint32_t* redf = (uint32_t*)(Blbuf + 1024);  // aliased in buf1; last read is
                                                 // strictly before buf1's first write

    const int bid = blockIdx.x;
    const int bm = bid >> 1;                 // 64-token tile
    const int nb0 = (bid & 1) * 512;
    const int tid = (int)threadIdx.x;
    const int wv = tid >> 6, lane = tid & 63, lrow = lane & 31, lh = lane >> 5;
    const int lgb = (wv & 1) * 2;            // wave's n-group pair within n-sub
    const int mrow0 = bm * 64 + (wv >> 1) * 32;

    float4 stgA[8], stgB[8];                 // statically-indexed only (rule #20)

// W chunk cc: thread covers ONE n-row (n = nb0 + nsub*128 + wv*32 + lrow),
// k-quarter (cc&3), its lh-half of each of 4 kf-sixteens: 8 float4 loads.
#define ISSUE(dst, cc) do {                                                        \
    const float4* ws_ = reinterpret_cast<const float4*>(W)                         \
        + ((size_t)(nb0 + ((cc) >> 2) * 128 + wv * 32 + lrow) * 64)                \
        + ((cc) & 3) * 16 + lh * 2;                                                \
    _Pragma("unroll") for (int w_ = 0; w_ < 4; ++w_) {                             \
        dst[2 * w_]     = ws_[w_ * 4];                                             \
        dst[2 * w_ + 1] = ws_[w_ * 4 + 1]; } } while (0)

// fragment slot = (g=wv)*256 + (kf=w)*64 + lane: every ds_write_b128 is
// wave-lane-contiguous (canonical free pattern).
#define WRITEB(src, cc) do {                                                       \
    uint4* bb_ = Blbuf + ((cc) & 1) * 1024 + wv * 256 + lane;                      \
    _Pragma("unroll") for (int w_ = 0; w_ < 4; ++w_)                               \
        bb_[w_ * 64] = pack8(src[2 * w_], src[2 * w_ + 1]); } while (0)

#define MFMA_CHUNK(cc) do {                                                        \
    const uint4* bb_ = Blbuf + ((cc) & 1) * 1024;                                  \
    const uint4* aa_ = Albuf + ((size_t)((wv >> 1) * 16 + ((cc) & 3) * 4)) * 64 + lane; \
    _Pragma("unroll") for (int kf_ = 0; kf_ < 4; ++kf_) {                          \
        bf16x8 av  = *reinterpret_cast<const bf16x8*>(&aa_[kf_ * 64]);             \
        bf16x8 bv0 = *reinterpret_cast<const bf16x8*>(&bb_[(lgb * 4 + kf_) * 64 + lane]); \
        bf16x8 bv1 = *reinterpret_cast<const bf16x8*>(&bb_[((lgb + 1) * 4 + kf_) * 64 + lane]); \
        acc0 = MFMA(av, bv0, acc0); acc1 = MFMA(av, bv1, acc1); } } while (0)

#define STORE_SUB(ss, bj0_, bj1_) do {                                             \
    const int col_ = nb0 + (ss) * 128 + lgb * 32 + lrow;                           \
    _Pragma("unroll") for (int r_ = 0; r_ < 16; ++r_) {                            \
        const int rowl_ = (r_ & 3) + 8 * (r_ >> 2) + 4 * lh;                       \
        const size_t o_ = (size_t)(mrow0 + rowl_) * HID + col_;                    \
        out[o_]      = acc0[r_] + bj0_;                                            \
        out[o_ + 32] = acc1[r_] + bj1_; }                                          \
    acc0 = (f32x16)(0.0f); acc1 = (f32x16)(0.0f); } while (0)

    // ---- issue chunk0 W loads first (latency hides under detect + SHA) ----
    ISSUE(stgA, 0);

    // ---- detect int64 vs int32 layout (first 8KB; odd words all-zero => int64) ----
    {
        const uint4* ids4 = reinterpret_cast<const uint4*>(ids32);
        uint4 da = ids4[tid], db = ids4[tid + 256];
        uint32_t z = da.y | da.w | db.y | db.w;
        unsigned long long m = __ballot(z != 0u);
        if (lane == 0) redf[wv] = (m != 0ull) ? 1u : 0u;
    }
    __syncthreads();
    const bool is64 = (redf[0] | redf[1] | redf[2] | redf[3]) == 0u;

    // biases for the 4 n-subtiles (issued early, parked in regs)
    const int cbase = nb0 + lgb * 32 + lrow;
    const float bb00 = bias[cbase +   0], bb01 = bias[cbase +  32];
    const float bb10 = bias[cbase + 128], bb11 = bias[cbase + 160];
    const float bb20 = bias[cbase + 256], bb21 = bias[cbase + 288];
    const float bb30 = bias[cbase + 384], bb31 = bias[cbase + 416];

    // ---- SHA + A fragments: threads 0..127 (64 tokens x 2 digests) ----
    if (tid < 128) {
        const int rr = tid >> 1;          // local token row (0..63)
        const uint32_t st = tid & 1;      // 0 = SHA-256, 1 = SHA-224
        const int tok = bm * 64 + rr;
        const uint32_t v = is64 ? ids32[2 * tok] : ids32[tok];

        // branchless decimal message
        const uint32_t q4 = __umulhi(v, 0xD1B71759u) >> 13;
        const uint32_t r4 = v - q4 * 10000u;
        const uint32_t q3 = __umulhi(r4, 0x10624DD3u) >> 6;
        const uint32_t r3 = r4 - q3 * 1000u;
        const uint32_t q2 = __umulhi(r3, 0x51EB851Fu) >> 5;
        const uint32_t r2 = r3 - q2 * 100u;
        const uint32_t q1 = __umulhi(r2, 0xCCCCCCCDu) >> 3;
        const uint32_t q0 = r2 - q1 * 10u;
        const uint32_t nd = v >= 10000u ? 5u : v >= 1000u ? 4u : v >= 100u ? 3u
                             : v >= 10u ? 2u : 1u;
        uint64_t M = ((uint64_t)(q4 + '0') << 56) | ((uint64_t)(q3 + '0') << 48) |
                     ((uint64_t)(q2 + '0') << 40) | ((uint64_t)(q1 + '0') << 32) |
                     ((uint64_t)(q0 + '0') << 24) | ((uint64_t)0x80u << 16);
        M <<= 8u * (5u - nd);

        uint32_t w0 = (uint32_t)(M >> 32), w1 = (uint32_t)M;
        uint32_t w2 = 0, w3 = 0, w4 = 0, w5 = 0, w6 = 0, w7 = 0;
        uint32_t w8 = 0, w9 = 0, w10 = 0, w11 = 0, w12 = 0, w13 = 0, w14 = 0;
        uint32_t w15 = nd * 8u;

        uint32_t sa = st ? 0xc1059ed8u : 0x6a09e667u;
        uint32_t sb = st ? 0x367cd507u : 0xbb67ae85u;
        uint32_t sc = st ? 0x3070dd17u : 0x3c6ef372u;
        uint32_t sd = st ? 0xf70e5939u : 0xa54ff53au;
        uint32_t se = st ? 0xffc00b31u : 0x510e527fu;
        uint32_t sf = st ? 0x68581511u : 0x9b05688cu;
        uint32_t sg = st ? 0x64f98fa7u : 0x1f83d9abu;
        uint32_t sh = st ? 0xbefa4fa4u : 0x5be0cd19u;

        // rounds 0-15
        RND1(0x428a2f98u, w0);  RND1(0x71374491u, w1);  RND1(0xb5c0fbcfu, w2);
        RND1(0xe9b5dba5u, w3);  RND1(0x3956c25bu, w4);  RND1(0x59f111f1u, w5);
        RND1(0x923f82a4u, w6);  RND1(0xab1c5ed5u, w7);  RND1(0xd807aa98u, w8);
        RND1(0x12835b01u, w9);  RND1(0x243185beu, w10); RND1(0x550c7dc3u, w11);
        RND1(0x72be5d74u, w12); RND1(0x80deb1feu, w13); RND1(0x9bdc06a7u, w14);
        RND1(0xc19bf174u, w15);
        // rounds 16-31
        WSXS(w0,w1,w9,w14);    RND1(0xe49b69c1u, w0);
        WSXS(w1,w2,w10,w15);   RND1(0xefbe4786u, w1);
        WSXS(w2,w3,w11,w0);    RND1(0x0fc19dc6u, w2);
        WSXS(w3,w4,w12,w1);    RND1(0x240ca1ccu, w3);
        WSXS(w4,w5,w13,w2);    RND1(0x2de92c6fu, w4);
        WSXS(w5,w6,w14,w3);    RND1(0x4a7484aau, w5);
        WSXS(w6,w7,w15,w4);    RND1(0x5cb0a9dcu, w6);
        WSXS(w7,w8,w0,w5);     RND1(0x76f988dau, w7);
        WSXS(w8,w9,w1,w6);     RND1(0x983e5152u, w8);
        WSXS(w9,w10,w2,w7);    RND1(0xa831c66du, w9);
        WSXS(w10,w11,w3,w8);   RND1(0xb00327c8u, w10);
        WSXS(w11,w12,w4,w9);   RND1(0xbf597fc7u, w11);
        WSXS(w12,w13,w5,w10);  RND1(0xc6e00bf3u, w12);
        WSXS(w13,w14,w6,w11);  RND1(0xd5a79147u, w13);
        WSXS(w14,w15,w7,w12);  RND1(0x06ca6351u, w14);
        WSXS(w15,w0,w8,w13);   RND1(0x14292967u, w15);
        // rounds 32-47
        WSXS(w0,w1,w9,w14);    RND1(0x27b70a85u, w0);
        WSXS(w1,w2,w10,w15);   RND1(0x2e1b2138u, w1);
        WSXS(w2,w3,w11,w0);    RND1(0x4d2c6dfcu, w2);
        WSXS(w3,w4,w12,w1);    RND1(0x53380d13u, w3);
        WSXS(w4,w5,w13,w2);    RND1(0x650a7354u, w4);
        WSXS(w5,w6,w14,w3);    RND1(0x766a0abbu, w5);
        WSXS(w6,w7,w15,w4);    RND1(0x81c2c92eu, w6);
        WSXS(w7,w8,w0,w5);     RND1(0x92722c85u, w7);
        WSXS(w8,w9,w1,w6);     RND1(0xa2bfe8a1u, w8);
        WSXS(w9,w10,w2,w7);    RND1(0xa81a664bu, w9);
        WSXS(w10,w11,w3,w8);   RND1(0xc24b8b70u, w10);
        WSXS(w11,w12,w4,w9);   RND1(0xc76c51a3u, w11);
        WSXS(w12,w13,w5,w10);  RND1(0xd192e819u, w12);
        WSXS(w13,w14,w6,w11);  RND1(0xd6990624u, w13);
        WSXS(w14,w15,w7,w12);  RND1(0xf40e3585u, w14);
        WSXS(w15,w0,w8,w13);   RND1(0x106aa070u, w15);
        // rounds 48-63
        WSXS(w0,w1,w9,w14);    RND1(0x19a4c116u, w0);
        WSXS(w1,w2,w10,w15);   RND1(0x1e376c08u, w1);
        WSXS(w2,w3,w11,w0);    RND1(0x2748774cu, w2);
        WSXS(w3,w4,w12,w1);    RND1(0x34b0bcb5u, w3);
        WSXS(w4,w5,w13,w2);    RND1(0x391c0cb3u, w4);
        WSXS(w5,w6,w14,w3);    RND1(0x4ed8aa4au, w5);
        WSXS(w6,w7,w15,w4);    RND1(0x5b9cca4fu, w6);
        WSXS(w7,w8,w0,w5);     RND1(0x682e6ff3u, w7);
        WSXS(w8,w9,w1,w6);     RND1(0x748f82eeu, w8);
        WSXS(w9,w10,w2,w7);    RND1(0x78a5636fu, w9);
        WSXS(w10,w11,w3,w8);   RND1(0x84c87814u, w10);
        WSXS(w11,w12,w4,w9);   RND1(0x8cc70208u, w11);
        WSXS(w12,w13,w5,w10);  RND1(0x90befffau, w12);
        WSXS(w13,w14,w6,w11);  RND1(0xa4506cebu, w13);
        WSXS(w14,w15,w7,w12);  RND1(0xbef9a3f7u, w14);
        WSXS(w15,w0,w8,w13);   RND1(0xc67178f2u, w15);

        const uint32_t hv = ((st ? 0xc1059ed8u : 0x6a09e667u) + sa) >> 24;
        const uint32_t hvo = __shfl_xor(hv, 1);           // partner's digest byte
        const uint32_t hv1 = st ? hvo : hv;               // sha256 byte
        const uint32_t hv2 = st ? hv : hvo;               // sha224 byte

        // A fragments: even thread kf 0..7 (k<128), odd kf 8..15
        const int ag = rr >> 5, aslot = rr & 31;
        uint32_t val = (hv1 + (st ? ((hv2 << 7) & 255u) : 0u)) & 255u;
        const int kfb = (int)st * 8;
#define PAIR(dst) { uint32_t lo_ = val; uint32_t hi_ = (val + hv2) & 255u;        \
                    val = (hi_ + hv2) & 255u;                                     \
                    dst = (__float_as_uint((float)lo_) >> 16) |                   \
                          (__float_as_uint((float)hi_) & 0xFFFF0000u); }
#pragma unroll
        for (int q = 0; q < 8; ++q) {
            uint32_t c0_, c1_, c2_, c3_, c4_, c5_, c6_, c7_;
            PAIR(c0_); PAIR(c1_); PAIR(c2_); PAIR(c3_);
            PAIR(c4_); PAIR(c5_); PAIR(c6_); PAIR(c7_);
            uint4 qa; qa.x = c0_; qa.y = c1_; qa.z = c2_; qa.w = c3_;
            uint4 qb; qb.x = c4_; qb.y = c5_; qb.z = c6_; qb.w = c7_;
            Albuf[(ag * 16 + kfb + q) * 64 + aslot]      = qa;   // k-half 0
            Albuf[(ag * 16 + kfb + q) * 64 + aslot + 32] = qb;   // k-half 1
        }
#undef PAIR
    }

    WRITEB(stgA, 0);    // chunk0 -> buf0
    ISSUE(stgB, 1);     // chunk1 loads in flight

    f32x16 acc0 = (f32x16)(0.0f), acc1 = (f32x16)(0.0f);

    __syncthreads();    // A complete + B chunk0 complete

    // ---- 16-chunk main loop (n-sub = c>>2, k-quarter = c&3), dbuf on c&1 ----
    ISSUE(stgA,  2); MFMA_CHUNK(0);                           WRITEB(stgB,  1); __syncthreads();
    ISSUE(stgB,  3); MFMA_CHUNK(1);                           WRITEB(stgA,  2); __syncthreads();
    ISSUE(stgA,  4); MFMA_CHUNK(2);                           WRITEB(stgB,  3); __syncthreads();
    ISSUE(stgB,  5); MFMA_CHUNK(3);  STORE_SUB(0, bb00, bb01); WRITEB(stgA,  4); __syncthreads();
    ISSUE(stgA,  6); MFMA_CHUNK(4);                           WRITEB(stgB,  5); __syncthreads();
    ISSUE(stgB,  7); MFMA_CHUNK(5);                           WRITEB(stgA,  6); __syncthreads();
    ISSUE(stgA,  8); MFMA_CHUNK(6);                           WRITEB(stgB,  7); __syncthreads();
    ISSUE(stgB,  9); MFMA_CHUNK(7);  STORE_SUB(1, bb10, bb11); WRITEB(stgA,  8); __syncthreads();
    ISSUE(stgA, 10); MFMA_CHUNK(8);                           WRITEB(stgB,  9); __syncthreads();
    ISSUE(stgB, 11); MFMA_CHUNK(9);                           WRITEB(stgA, 10); __syncthreads();
    ISSUE(stgA, 12); MFMA_CHUNK(10);                          WRITEB(stgB, 11); __syncthreads();
    ISSUE(stgB, 13); MFMA_CHUNK(11); STORE_SUB(2, bb20, bb21); WRITEB(stgA, 12); __syncthreads();
    ISSUE(stgA, 14); MFMA_CHUNK(12);                          WRITEB(stgB, 13); __syncthreads();
    ISSUE(stgB, 15); MFMA_CHUNK(13);                          WRITEB(stgA, 14); __syncthreads();
                     MFMA_CHUNK(14);                          WRITEB(stgB, 15); __syncthreads();
                     MFMA_CHUNK(15); STORE_SUB(3, bb30, bb31);

#undef ISSUE
#undef WRITEB
#undef MFMA_CHUNK
#undef STORE_SUB
}

extern "C" void kernel_launch(void* const* d_in, const int* in_sizes, int n_in,
                              void* d_out, int out_size, void* d_ws, size_t ws_size,
                              hipStream_t stream) {
    const uint32_t* ids32 = (const uint32_t*)d_in[0];
    const float* W = (const float*)d_in[1];
    const float* bias = (const float*)d_in[2];
    float* out = (float*)d_out;
    (void)d_ws; (void)ws_size; (void)in_sizes; (void)n_in; (void)out_size;

    fused_kernel<<<512, 256, 0, stream>>>(ids32, W, bias, out);
}

// Round 9
// 34.981 us; speedup vs baseline: 1.3229x; 1.3229x over previous
//
#include <hip/hip_runtime.h>
#include <stdint.h>

typedef short bf16x8 __attribute__((ext_vector_type(8)));
typedef float f32x16 __attribute__((ext_vector_type(16)));
typedef unsigned short ushort_t;

#define EMB 256
#define HID 1024
#define NTOK 16384

// ws: Wf fragment-ordered bf16 [32 g][16 kf][64 lane][8 elem] = 512 KB
#define WS_W_OFF 0

// ---------------- SHA-256/224 primitives (proven R4-R8) ----------------
#define ROTR(x,n) (((x)>>(n))|((x)<<(32-(n))))
#define S0F(x) (ROTR((x),7)^ROTR((x),18)^((x)>>3))
#define S1F(x) (ROTR((x),17)^ROTR((x),19)^((x)>>10))

#define RND1(Kc, Wt) do {                                                          \
    uint32_t t1_ = sh + (ROTR(se,6)^ROTR(se,11)^ROTR(se,25))                       \
                   + ((se&sf)^(~se&sg)) + (Kc) + (Wt);                             \
    uint32_t t2_ = (ROTR(sa,2)^ROTR(sa,13)^ROTR(sa,22))                            \
                   + ((sa&sb)^(sa&sc)^(sb&sc));                                    \
    sh=sg; sg=sf; sf=se; se=sd+t1_; sd=sc; sc=sb; sb=sa; sa=t1_+t2_; } while (0)

#define WSXS(a,b,c,d) ((a) += S0F(b) + (c) + S1F(d))

__device__ __forceinline__ uint32_t rbf(float x) {
    uint32_t b = __float_as_uint(x);
    return (b + 0x7FFFu + ((b >> 16) & 1u)) >> 16;   // fp32 -> bf16 RNE
}
__device__ __forceinline__ uint4 pack8(float4 a, float4 b) {
    uint4 q;
    q.x = rbf(a.x) | (rbf(a.y) << 16);
    q.y = rbf(a.z) | (rbf(a.w) << 16);
    q.z = rbf(b.x) | (rbf(b.y) << 16);
    q.w = rbf(b.z) | (rbf(b.w) << 16);
    return q;
}

#define MFMA(av,bv,acc) __builtin_amdgcn_mfma_f32_32x32x16_bf16(av,bv,acc,0,0,0)

// Prepass: W fp32 -> fragment-ordered bf16 Wf (R5-proven mapping).
// Thread t: row h = t>>4, k-chunk kk = t&15 (16 floats).
__global__ __launch_bounds__(256) void prep_kernel(const float* __restrict__ W,
                                                   ushort_t* __restrict__ Wf) {
    const int t = blockIdx.x * 256 + threadIdx.x;   // 16384 threads
    const int h = t >> 4;
    const int kk = t & 15;
    const float4* wsrc = reinterpret_cast<const float4*>(W + h * EMB + kk * 16);
    float4 a = wsrc[0], b = wsrc[1], c = wsrc[2], d = wsrc[3];
    uint4 qa = pack8(a, b);
    uint4 qb = pack8(c, d);
    uint4* wbase = reinterpret_cast<uint4*>(Wf) + ((size_t)(h >> 5) * 16 + kk) * 64 + (h & 31);
    wbase[0]  = qa;   // k-half 0
    wbase[32] = qb;   // k-half 1
}

// Main: detect + SHA->A-LDS (once) + GEMM with B-fragments read directly from
// L2-hot Wf (wave-contiguous 1KB bursts), zero barriers in the compute loop,
// nontemporal streamed stores. Grid 512 x 256 thr; block = 128 tok x 256 n;
// LDS 64KB -> 2 blocks/CU (8 waves/CU). Wave = 2M x 2N, 4 acc.
__global__ __launch_bounds__(256, 2) void fused_kernel(const uint32_t* __restrict__ ids32,
                                                       const ushort_t* __restrict__ Wf,
                                                       const float* __restrict__ bias,
                                                       float* __restrict__ out) {
    __shared__ uint4 Albuf[4096];   // A: [4 g][16 kf][64 lane] x 16B = 64KB
    __shared__ uint32_t redf[4];

    const int bid = blockIdx.x;
    const int bm = bid >> 2;                 // 128-token tile
    const int nb0 = (bid & 3) * 256;         // n-quarter
    const int tid = (int)threadIdx.x;
    const int wv = tid >> 6, lane = tid & 63, lrow = lane & 31, lh = lane >> 5;
    const int wm = wv >> 1, wn = wv & 1;

    // ---- detect int64 vs int32 (first 8KB; odd words all-zero => int64) ----
    {
        const uint4* ids4 = reinterpret_cast<const uint4*>(ids32);
        uint4 da = ids4[tid], db = ids4[tid + 256];
        uint32_t z = da.y | da.w | db.y | db.w;
        unsigned long long m = __ballot(z != 0u);
        if (lane == 0) redf[wv] = (m != 0ull) ? 1u : 0u;
    }
    __syncthreads();
    const bool is64 = (redf[0] | redf[1] | redf[2] | redf[3]) == 0u;

    // ---- SHA: all 256 threads = 128 tokens x 2 digests (R6-proven) ----
    const int rr = tid >> 1;
    const uint32_t st = tid & 1;
    const int tok = bm * 128 + rr;
    const uint32_t v = is64 ? ids32[2 * tok] : ids32[tok];

    const uint32_t q4 = __umulhi(v, 0xD1B71759u) >> 13;
    const uint32_t r4 = v - q4 * 10000u;
    const uint32_t q3 = __umulhi(r4, 0x10624DD3u) >> 6;
    const uint32_t r3 = r4 - q3 * 1000u;
    const uint32_t q2 = __umulhi(r3, 0x51EB851Fu) >> 5;
    const uint32_t r2 = r3 - q2 * 100u;
    const uint32_t q1 = __umulhi(r2, 0xCCCCCCCDu) >> 3;
    const uint32_t q0 = r2 - q1 * 10u;
    const uint32_t nd = v >= 10000u ? 5u : v >= 1000u ? 4u : v >= 100u ? 3u
                         : v >= 10u ? 2u : 1u;
    uint64_t M = ((uint64_t)(q4 + '0') << 56) | ((uint64_t)(q3 + '0') << 48) |
                 ((uint64_t)(q2 + '0') << 40) | ((uint64_t)(q1 + '0') << 32) |
                 ((uint64_t)(q0 + '0') << 24) | ((uint64_t)0x80u << 16);
    M <<= 8u * (5u - nd);

    uint32_t w0 = (uint32_t)(M >> 32), w1 = (uint32_t)M;
    uint32_t w2 = 0, w3 = 0, w4 = 0, w5 = 0, w6 = 0, w7 = 0;
    uint32_t w8 = 0, w9 = 0, w10 = 0, w11 = 0, w12 = 0, w13 = 0, w14 = 0;
    uint32_t w15 = nd * 8u;

    uint32_t sa = st ? 0xc1059ed8u : 0x6a09e667u;
    uint32_t sb = st ? 0x367cd507u : 0xbb67ae85u;
    uint32_t sc = st ? 0x3070dd17u : 0x3c6ef372u;
    uint32_t sd = st ? 0xf70e5939u : 0xa54ff53au;
    uint32_t se = st ? 0xffc00b31u : 0x510e527fu;
    uint32_t sf = st ? 0x68581511u : 0x9b05688cu;
    uint32_t sg = st ? 0x64f98fa7u : 0x1f83d9abu;
    uint32_t sh = st ? 0xbefa4fa4u : 0x5be0cd19u;

    // rounds 0-15
    RND1(0x428a2f98u, w0);  RND1(0x71374491u, w1);  RND1(0xb5c0fbcfu, w2);
    RND1(0xe9b5dba5u, w3);  RND1(0x3956c25bu, w4);  RND1(0x59f111f1u, w5);
    RND1(0x923f82a4u, w6);  RND1(0xab1c5ed5u, w7);  RND1(0xd807aa98u, w8);
    RND1(0x12835b01u, w9);  RND1(0x243185beu, w10); RND1(0x550c7dc3u, w11);
    RND1(0x72be5d74u, w12); RND1(0x80deb1feu, w13); RND1(0x9bdc06a7u, w14);
    RND1(0xc19bf174u, w15);
    // rounds 16-31
    WSXS(w0,w1,w9,w14);    RND1(0xe49b69c1u, w0);
    WSXS(w1,w2,w10,w15);   RND1(0xefbe4786u, w1);
    WSXS(w2,w3,w11,w0);    RND1(0x0fc19dc6u, w2);
    WSXS(w3,w4,w12,w1);    RND1(0x240ca1ccu, w3);
    WSXS(w4,w5,w13,w2);    RND1(0x2de92c6fu, w4);
    WSXS(w5,w6,w14,w3);    RND1(0x4a7484aau, w5);
    WSXS(w6,w7,w15,w4);    RND1(0x5cb0a9dcu, w6);
    WSXS(w7,w8,w0,w5);     RND1(0x76f988dau, w7);
    WSXS(w8,w9,w1,w6);     RND1(0x983e5152u, w8);
    WSXS(w9,w10,w2,w7);    RND1(0xa831c66du, w9);
    WSXS(w10,w11,w3,w8);   RND1(0xb00327c8u, w10);
    WSXS(w11,w12,w4,w9);   RND1(0xbf597fc7u, w11);
    WSXS(w12,w13,w5,w10);  RND1(0xc6e00bf3u, w12);
    WSXS(w13,w14,w6,w11);  RND1(0xd5a79147u, w13);
    WSXS(w14,w15,w7,w12);  RND1(0x06ca6351u, w14);
    WSXS(w15,w0,w8,w13);   RND1(0x14292967u, w15);
    // rounds 32-47
    WSXS(w0,w1,w9,w14);    RND1(0x27b70a85u, w0);
    WSXS(w1,w2,w10,w15);   RND1(0x2e1b2138u, w1);
    WSXS(w2,w3,w11,w0);    RND1(0x4d2c6dfcu, w2);
    WSXS(w3,w4,w12,w1);    RND1(0x53380d13u, w3);
    WSXS(w4,w5,w13,w2);    RND1(0x650a7354u, w4);
    WSXS(w5,w6,w14,w3);    RND1(0x766a0abbu, w5);
    WSXS(w6,w7,w15,w4);    RND1(0x81c2c92eu, w6);
    WSXS(w7,w8,w0,w5);     RND1(0x92722c85u, w7);
    WSXS(w8,w9,w1,w6);     RND1(0xa2bfe8a1u, w8);
    WSXS(w9,w10,w2,w7);    RND1(0xa81a664bu, w9);
    WSXS(w10,w11,w3,w8);   RND1(0xc24b8b70u, w10);
    WSXS(w11,w12,w4,w9);   RND1(0xc76c51a3u, w11);
    WSXS(w12,w13,w5,w10);  RND1(0xd192e819u, w12);
    WSXS(w13,w14,w6,w11);  RND1(0xd6990624u, w13);
    WSXS(w14,w15,w7,w12);  RND1(0xf40e3585u, w14);
    WSXS(w15,w0,w8,w13);   RND1(0x106aa070u, w15);
    // rounds 48-63
    WSXS(w0,w1,w9,w14);    RND1(0x19a4c116u, w0);
    WSXS(w1,w2,w10,w15);   RND1(0x1e376c08u, w1);
    WSXS(w2,w3,w11,w0);    RND1(0x2748774cu, w2);
    WSXS(w3,w4,w12,w1);    RND1(0x34b0bcb5u, w3);
    WSXS(w4,w5,w13,w2);    RND1(0x391c0cb3u, w4);
    WSXS(w5,w6,w14,w3);    RND1(0x4ed8aa4au, w5);
    WSXS(w6,w7,w15,w4);    RND1(0x5b9cca4fu, w6);
    WSXS(w7,w8,w0,w5);     RND1(0x682e6ff3u, w7);
    WSXS(w8,w9,w1,w6);     RND1(0x748f82eeu, w8);
    WSXS(w9,w10,w2,w7);    RND1(0x78a5636fu, w9);
    WSXS(w10,w11,w3,w8);   RND1(0x84c87814u, w10);
    WSXS(w11,w12,w4,w9);   RND1(0x8cc70208u, w11);
    WSXS(w12,w13,w5,w10);  RND1(0x90befffau, w12);
    WSXS(w13,w14,w6,w11);  RND1(0xa4506cebu, w13);
    WSXS(w14,w15,w7,w12);  RND1(0xbef9a3f7u, w14);
    WSXS(w15,w0,w8,w13);   RND1(0xc67178f2u, w15);

    const uint32_t hv = ((st ? 0xc1059ed8u : 0x6a09e667u) + sa) >> 24;
    const uint32_t hvo = __shfl_xor(hv, 1);           // partner's digest byte
    const uint32_t hv1 = st ? hvo : hv;               // sha256 byte
    const uint32_t hv2 = st ? hv : hvo;               // sha224 byte

    // ---- A fragments: even thread kf 0..7 (k<128), odd kf 8..15 ----
    {
        const int ag = rr >> 5, aslot = rr & 31;
        uint32_t val = (hv1 + (st ? ((hv2 << 7) & 255u) : 0u)) & 255u;
        const int kfb = (int)st * 8;
#define PAIR(dst) { uint32_t lo_ = val; uint32_t hi_ = (val + hv2) & 255u;        \
                    val = (hi_ + hv2) & 255u;                                     \
                    dst = (__float_as_uint((float)lo_) >> 16) |                   \
                          (__float_as_uint((float)hi_) & 0xFFFF0000u); }
#pragma unroll
        for (int q = 0; q < 8; ++q) {
            uint32_t c0_, c1_, c2_, c3_, c4_, c5_, c6_, c7_;
            PAIR(c0_); PAIR(c1_); PAIR(c2_); PAIR(c3_);
            PAIR(c4_); PAIR(c5_); PAIR(c6_); PAIR(c7_);
            uint4 qa; qa.x = c0_; qa.y = c1_; qa.z = c2_; qa.w = c3_;
            uint4 qb; qb.x = c4_; qb.y = c5_; qb.z = c6_; qb.w = c7_;
            Albuf[(ag * 16 + kfb + q) * 64 + aslot]      = qa;   // k-half 0
            Albuf[(ag * 16 + kfb + q) * 64 + aslot + 32] = qb;   // k-half 1
        }
#undef PAIR
    }

    // biases (column-dependent only)
    const int cb = nb0 + wn * 64 + lrow;
    const float bs00 = bias[cb],       bs01 = bias[cb + 32];
    const float bs10 = bias[cb + 128], bs11 = bias[cb + 160];

    __syncthreads();    // A complete; no more barriers below

    const bf16x8* bfr = reinterpret_cast<const bf16x8*>(Wf);
    const bf16x8* alr = reinterpret_cast<const bf16x8*>(Albuf);
    const int agA0 = (wm * 2) * 16, agA1 = (wm * 2 + 1) * 16;
    const int m0 = bm * 128 + wm * 64;

// one 128-col n-sub: full K, 4 accs, B-frags straight from L2-hot Wf
#define DO_SUB(sub, bj0_, bj1_) do {                                               \
    const int gb0_ = (nb0 >> 5) + (sub) * 4 + wn * 2;                              \
    f32x16 a00 = (f32x16)(0.0f), a01 = (f32x16)(0.0f);                             \
    f32x16 a10 = (f32x16)(0.0f), a11 = (f32x16)(0.0f);                             \
    _Pragma("unroll 2")                                                            \
    for (int kf = 0; kf < 16; ++kf) {                                              \
        bf16x8 bv0 = bfr[((size_t)(gb0_ * 16 + kf)) * 64 + lane];                  \
        bf16x8 bv1 = bfr[((size_t)((gb0_ + 1) * 16 + kf)) * 64 + lane];            \
        bf16x8 av0 = alr[(agA0 + kf) * 64 + lane];                                 \
        bf16x8 av1 = alr[(agA1 + kf) * 64 + lane];                                 \
        a00 = MFMA(av0, bv0, a00); a01 = MFMA(av0, bv1, a01);                      \
        a10 = MFMA(av1, bv0, a10); a11 = MFMA(av1, bv1, a11);                      \
    }                                                                              \
    const int col_ = nb0 + (sub) * 128 + wn * 64 + lrow;                           \
    _Pragma("unroll")                                                              \
    for (int r_ = 0; r_ < 16; ++r_) {                                              \
        const int rowl_ = (r_ & 3) + 8 * (r_ >> 2) + 4 * lh;                       \
        const size_t o0_ = (size_t)(m0 + rowl_) * HID + col_;                      \
        const size_t o1_ = o0_ + (size_t)32 * HID;                                 \
        __builtin_nontemporal_store(a00[r_] + bj0_, &out[o0_]);                    \
        __builtin_nontemporal_store(a01[r_] + bj1_, &out[o0_ + 32]);               \
        __builtin_nontemporal_store(a10[r_] + bj0_, &out[o1_]);                    \
        __builtin_nontemporal_store(a11[r_] + bj1_, &out[o1_ + 32]);               \
    } } while (0)

    DO_SUB(0, bs00, bs01);
    DO_SUB(1, bs10, bs11);

#undef DO_SUB
}

extern "C" void kernel_launch(void* const* d_in, const int* in_sizes, int n_in,
                              void* d_out, int out_size, void* d_ws, size_t ws_size,
                              hipStream_t stream) {
    const uint32_t* ids32 = (const uint32_t*)d_in[0];
    const float* W = (const float*)d_in[1];
    const float* bias = (const float*)d_in[2];
    float* out = (float*)d_out;
    ushort_t* Wf = (ushort_t*)((char*)d_ws + WS_W_OFF);
    (void)in_sizes; (void)n_in; (void)out_size; (void)ws_size;

    prep_kernel<<<64, 256, 0, stream>>>(W, Wf);
    fused_kernel<<<512, 256, 0, stream>>>(ids32, Wf, bias, out);
}